// Round 24
// baseline (504.513 us; speedup 1.0000x reference)
//
#include <hip/hip_runtime.h>
#include <stdint.h>

// LSTM B=256,T=2048,D=U=64 fp32. 256 WGs (1 batch) x 256 thr (4 waves).
// R24 = R22 (498us, best) + two serial-chain cuts:
//  1) scaled cell state: recurrence carries cK = 2*log2e*c.
//     cK = gf*cK + gi*ggk, ggk = fmaf(4*log2e, sigm2(zg), -2*log2e).
//     tanh arg is then exp2(cK) DIRECTLY (the per-step mul feeding exp2
//     leaves the chain). True c = cK*(ln2/2) computed on the deferred
//     store path (off-chain).
//  2) chunk-boundary A-read hoist: s=0's h was published before the
//     previous chunk's last barrier, so its A-read issues BEFORE the xz
//     production block; its latency hides under the 8 xz MFMAs+scatter.
// Everything else = R22: counted-lgkm barrier (publish-first, xz read,
// lgkmcnt(1)), exp2 pre-scaling in weights (cand gate 2x), branch-free
// tanh, replicated-A h-MFMA (zero-C, 2-deep), xz per 16-step chunk via
// MFMA rows=timesteps into wave-private sXZ, deferred global stores in
// the A-read shadow, one barrier per step, vmcnt never drained.
// k-map f(g,e)=g*8+e on BOTH A and B; C/D layout m89-verified.

#define T_STEPS 2048
#define DIM     64
#define GATES   256
#define CHUNK   16
#define NCHUNK  (T_STEPS / CHUNK)

typedef _Float16 f16;
typedef _Float16 f16x8 __attribute__((ext_vector_type(8)));
typedef float    f32x4 __attribute__((ext_vector_type(4)));

#define LOG2E   1.44269504088896f
#define N2LOG2E 2.88539008177793f    // 2*log2(e)
#define N4LOG2E 5.77078016355586f    // 4*log2(e)
#define INVK    0.34657359027997f    // ln2/2 = 1/(2*log2e)

__device__ __forceinline__ float sigm2(float zl) {   // zl = z*log2e
    return __builtin_amdgcn_rcpf(1.f + __builtin_amdgcn_exp2f(-zl));
}

#define MFMA16(A, B, C) __builtin_amdgcn_mfma_f32_16x16x32_f16(A, B, C, 0, 0, 0)

__device__ __forceinline__ void pack8(f16x8& d, const float4& a, const float4& b) {
    d[0]=(f16)a.x; d[1]=(f16)a.y; d[2]=(f16)a.z; d[3]=(f16)a.w;
    d[4]=(f16)b.x; d[5]=(f16)b.y; d[6]=(f16)b.z; d[7]=(f16)b.w;
}

__global__ __launch_bounds__(256, 1)
void lstm_r24_kernel(const float* __restrict__ x,
                     const float* __restrict__ Wx,
                     const float* __restrict__ Wh,
                     const float* __restrict__ bias,
                     float* __restrict__ out)
{
    __shared__ __align__(16) f16   sH[2][64];             // h dbuf (f16)
    __shared__ __align__(16) float sXZ[4][CHUNK][16][4];  // wave-private xz

    const int tid  = threadIdx.x;
    const int lane = tid & 63;
    const int w    = tid >> 6;       // wave 0..3 -> units w*16..+16
    const int j    = lane & 15;      // col-in-tile (B,D) / row (A, xz MFMA)
    const int g    = lane >> 4;      // k-group: k = ks*32 + g*8 + e
    const int u    = w * 16 + j;     // unit

    const int batch = blockIdx.x;
    const float* xb = x + (size_t)batch * T_STEPS * DIM;
    float* ob = out + (size_t)batch * T_STEPS * (2 * DIM);

    // ---- persistent B fragments, pre-scaled: gate q scale = log2e, except
    // candidate gate (q==2) scale = 2*log2e (removes per-step zg doubling).
    f16x8 Bh[4][2], Bx[4][2];
    f32x4 bias4[4];
#pragma unroll
    for (int q = 0; q < 4; ++q) {
        const float sc = (q == 2) ? N2LOG2E : LOG2E;
        const int col = q * 64 + u;
        const float bb = bias[col] * sc;
        bias4[q][0] = bb; bias4[q][1] = bb; bias4[q][2] = bb; bias4[q][3] = bb;
#pragma unroll
        for (int ks = 0; ks < 2; ++ks)
#pragma unroll
            for (int e = 0; e < 8; ++e) {
                const int k = ks * 32 + g * 8 + e;
                Bh[q][ks][e] = (f16)(Wh[k * GATES + col] * sc);
                Bx[q][ks][e] = (f16)(Wx[k * GATES + col] * sc);
            }
    }
    const f32x4 zero4 = {0.f, 0.f, 0.f, 0.f};

    if (tid < 128) sH[tid >> 6][tid & 63] = (f16)0.f;

    // ---- prefetch x chunk 0: A row = ts = j, feats g*8.. ----
    float4 x0, x1, x2, x3;
    {
        const float* xr = xb + (size_t)j * DIM + g * 8;
        x0 = *(const float4*)(xr);      x1 = *(const float4*)(xr + 4);
        x2 = *(const float4*)(xr + 32); x3 = *(const float4*)(xr + 36);
    }

    float cK = 0.f;  // scaled cell state 2*log2e*c, replicated per lane group
    float pc = 0.f, ph = 0.f;   // deferred-store copies of last step's (c,h)
    __syncthreads();

#pragma unroll 1
    for (int n = 0; n < NCHUNK; ++n) {
        // s=0 A-read HOISTED above xz production: h(16n) was published
        // before the previous chunk's last barrier -> data is ready, and
        // its latency hides under the xz MFMAs below.
        f16x8 A0c = *(const f16x8*)&sH[0][g * 8];
        f16x8 A1c = *(const f16x8*)&sH[0][32 + g * 8];

        // ---- xz chunk: z[q] = bias + X_chunk @ Wx (rows = 16 ts) ----
        f16x8 ax0, ax1;
        pack8(ax0, x0, x1); pack8(ax1, x2, x3);
        f32x4 z0 = MFMA16(ax0, Bx[0][0], bias4[0]); z0 = MFMA16(ax1, Bx[0][1], z0);
        f32x4 z1 = MFMA16(ax0, Bx[1][0], bias4[1]); z1 = MFMA16(ax1, Bx[1][1], z1);
        f32x4 z2 = MFMA16(ax0, Bx[2][0], bias4[2]); z2 = MFMA16(ax1, Bx[2][1], z2);
        f32x4 z3 = MFMA16(ax0, Bx[3][0], bias4[3]); z3 = MFMA16(ax1, Bx[3][1], z3);
        // scatter to wave-private sXZ: row = 4g+r (D-layout), unit j
#pragma unroll
        for (int r = 0; r < 4; ++r) {
            float4 v = {z0[r], z1[r], z2[r], z3[r]};
            *(float4*)&sXZ[w][4 * g + r][j][0] = v;
        }
        // s=0 xz read: DS in-wave program order -> consistent, no drain
        float4 xzv = *(const float4*)&sXZ[w][0][j][0];

        // prefetch next chunk's x (returns during the 16 steps below)
        if (n + 1 < NCHUNK) {
            const float* xr = xb + ((size_t)(n + 1) * CHUNK + j) * DIM + g * 8;
            x0 = *(const float4*)(xr);      x1 = *(const float4*)(xr + 4);
            x2 = *(const float4*)(xr + 32); x3 = *(const float4*)(xr + 36);
        }

        float* obn = ob + (size_t)n * CHUNK * 128;

#pragma unroll
        for (int s = 0; s < CHUNK; ++s) {
            const int pb = s & 1;
            // A-reads first post-barrier (s=0: hoisted pre-chunk copies)
            f16x8 A0 = (s == 0) ? A0c : *(const f16x8*)&sH[pb][g * 8];
            f16x8 A1 = (s == 0) ? A1c : *(const f16x8*)&sH[pb][32 + g * 8];

            // deferred store of step t-1 (fills the A-read latency shadow)
            if (s > 0 || n > 0) {
                float* prevP = obn + (s - 1) * 128;       // s==0 -> prev chunk
                if (g == 0)      prevP[u]      = pc;       // cell out
                else if (g == 1) prevP[64 + u] = ph;       // hidden out
            }

            f32x4 h0 = MFMA16(A0, Bh[0][0], zero4); h0 = MFMA16(A1, Bh[0][1], h0);
            f32x4 h1 = MFMA16(A0, Bh[1][0], zero4); h1 = MFMA16(A1, Bh[1][1], h1);
            f32x4 h2 = MFMA16(A0, Bh[2][0], zero4); h2 = MFMA16(A1, Bh[2][1], h2);
            f32x4 h3 = MFMA16(A0, Bh[3][0], zero4); h3 = MFMA16(A1, Bh[3][1], h3);

            float zi = h0[0] + xzv.x, zf = h1[0] + xzv.y;
            float zg = h2[0] + xzv.z, zo = h3[0] + xzv.w;
            float gi = sigm2(zi), gf = sigm2(zf), go = sigm2(zo);
            // ggk = (2*log2e)*gg: folds the exp2 pre-scale into the constants
            float ggk = fmaf(N4LOG2E, sigm2(zg), -N2LOG2E);
            cK = fmaf(gf, cK, gi * ggk);
            // branch-free tanh on pre-scaled state: exp2(cK) directly
            float ep = __builtin_amdgcn_exp2f(cK);
            float th = fmaf(-2.f, __builtin_amdgcn_rcpf(1.f + ep), 1.f);
            float hh = go * th;

            // ---- counted-lgkm barrier sequence ----
            if (g == 2) sH[pb ^ 1][u] = (f16)hh;          // publish FIRST
            __builtin_amdgcn_sched_barrier(0);
            float4 xzn = *(const float4*)&sXZ[w][(s + 1) & 15][j][0];
            __builtin_amdgcn_sched_barrier(0);
            asm volatile("s_waitcnt lgkmcnt(1)" ::: "memory");
            __builtin_amdgcn_sched_barrier(0);
            __builtin_amdgcn_s_barrier();
            __builtin_amdgcn_sched_barrier(0);

            pc = cK * INVK;      // true c, computed off the critical chain
            ph = hh;
            xzv = xzn;
        }
    }
    // epilogue: store final step t = T-1
    {
        float* prevP = ob + (size_t)(T_STEPS - 1) * 128;
        if (g == 0)      prevP[u]      = pc;
        else if (g == 1) prevP[64 + u] = ph;
    }
}

extern "C" void kernel_launch(void* const* d_in, const int* in_sizes, int n_in,
                              void* d_out, int out_size, void* d_ws, size_t ws_size,
                              hipStream_t stream) {
    const float* x  = (const float*)d_in[0];
    const float* Wx = (const float*)d_in[1];
    const float* Wh = (const float*)d_in[2];
    const float* b  = (const float*)d_in[3];
    float* out = (float*)d_out;

    hipLaunchKernelGGL(lstm_r24_kernel, dim3(256), dim3(256), 0, stream,
                       x, Wx, Wh, b, out);
}

// Round 25
// 496.663 us; speedup vs baseline: 1.0158x; 1.0158x over previous
//
#include <hip/hip_runtime.h>
#include <stdint.h>

// LSTM B=256,T=2048,D=U=64 fp32. 256 WGs (1 batch) x 256 thr (4 waves).
// FINAL (= R22, best at 498.6us; R24's extra hoists regressed and are
// reverted). Structure and why each piece exists:
//  - MFMA-based dots (R9): any VALU-delivery scheme floors at ~900us.
//  - replicated-A h-MFMA, persistent zero-C (R13): z for every gate column
//    lands in every lane at reg 0 -> no bpermute/migration/acc re-init.
//  - xz = bias + X_chunk @ Wx per 16-step chunk via MFMA (rows=timesteps)
//    into wave-private sXZ; per-step read = one broadcast b128, rotated
//    pre-barrier (R15).
//  - deferred global stores: issued one step late in the A-read latency
//    shadow (R20, -6%).
//  - counted-lgkm barrier: publish-first sH write, then xz prefetch read,
//    s_waitcnt lgkmcnt(1) -> write drained, read stays in flight across
//    s_barrier (R21, -4%).
//  - exp2 pre-scaling: log2e folded into weights/bias (cand gate 2x) ->
//    v_exp_f32 direct; branch-free tanh via exp2 saturation (R22, -4%).
// Latency floor: step ~584cyc, serial chain ~430cyc (barrier + cross-wave
// h ds_read + MFMA + 4 transcendentals); no pipe >35% busy. R11/R14/R16/
// R17/R18/R19/R24 all tested alternatives and regressed.
// k-map f(g,e)=g*8+e on BOTH A and B; C/D layout m89-verified.

#define T_STEPS 2048
#define DIM     64
#define GATES   256
#define CHUNK   16
#define NCHUNK  (T_STEPS / CHUNK)

typedef _Float16 f16;
typedef _Float16 f16x8 __attribute__((ext_vector_type(8)));
typedef float    f32x4 __attribute__((ext_vector_type(4)));

#define LOG2E   1.44269504088896f
#define N2LOG2E 2.88539008177793f   // 2*log2(e)

__device__ __forceinline__ float sigm2(float zl) {   // zl = z*log2e
    return __builtin_amdgcn_rcpf(1.f + __builtin_amdgcn_exp2f(-zl));
}

#define MFMA16(A, B, C) __builtin_amdgcn_mfma_f32_16x16x32_f16(A, B, C, 0, 0, 0)

__device__ __forceinline__ void pack8(f16x8& d, const float4& a, const float4& b) {
    d[0]=(f16)a.x; d[1]=(f16)a.y; d[2]=(f16)a.z; d[3]=(f16)a.w;
    d[4]=(f16)b.x; d[5]=(f16)b.y; d[6]=(f16)b.z; d[7]=(f16)b.w;
}

__global__ __launch_bounds__(256, 1)
void lstm_final_kernel(const float* __restrict__ x,
                       const float* __restrict__ Wx,
                       const float* __restrict__ Wh,
                       const float* __restrict__ bias,
                       float* __restrict__ out)
{
    __shared__ __align__(16) f16   sH[2][64];             // h dbuf (f16)
    __shared__ __align__(16) float sXZ[4][CHUNK][16][4];  // wave-private xz

    const int tid  = threadIdx.x;
    const int lane = tid & 63;
    const int w    = tid >> 6;       // wave 0..3 -> units w*16..+16
    const int j    = lane & 15;      // col-in-tile (B,D) / row (A, xz MFMA)
    const int g    = lane >> 4;      // k-group: k = ks*32 + g*8 + e
    const int u    = w * 16 + j;     // unit

    const int batch = blockIdx.x;
    const float* xb = x + (size_t)batch * T_STEPS * DIM;
    float* ob = out + (size_t)batch * T_STEPS * (2 * DIM);

    // ---- persistent B fragments, pre-scaled: gate q scale = log2e, except
    // candidate gate (q==2) scale = 2*log2e (removes per-step zg doubling).
    f16x8 Bh[4][2], Bx[4][2];
    f32x4 bias4[4];
#pragma unroll
    for (int q = 0; q < 4; ++q) {
        const float sc = (q == 2) ? N2LOG2E : LOG2E;
        const int col = q * 64 + u;
        const float bb = bias[col] * sc;
        bias4[q][0] = bb; bias4[q][1] = bb; bias4[q][2] = bb; bias4[q][3] = bb;
#pragma unroll
        for (int ks = 0; ks < 2; ++ks)
#pragma unroll
            for (int e = 0; e < 8; ++e) {
                const int k = ks * 32 + g * 8 + e;
                Bh[q][ks][e] = (f16)(Wh[k * GATES + col] * sc);
                Bx[q][ks][e] = (f16)(Wx[k * GATES + col] * sc);
            }
    }
    const f32x4 zero4 = {0.f, 0.f, 0.f, 0.f};

    if (tid < 128) sH[tid >> 6][tid & 63] = (f16)0.f;

    // ---- prefetch x chunk 0: A row = ts = j, feats g*8.. ----
    float4 x0, x1, x2, x3;
    {
        const float* xr = xb + (size_t)j * DIM + g * 8;
        x0 = *(const float4*)(xr);      x1 = *(const float4*)(xr + 4);
        x2 = *(const float4*)(xr + 32); x3 = *(const float4*)(xr + 36);
    }

    float c = 0.f;   // replicated: every lane-group's lane j holds c[u]
    float pc = 0.f, ph = 0.f;   // deferred-store copies of last step's (c,h)
    __syncthreads();

#pragma unroll 1
    for (int n = 0; n < NCHUNK; ++n) {
        // ---- xz chunk: z[q] = bias + X_chunk @ Wx (rows = 16 ts) ----
        f16x8 ax0, ax1;
        pack8(ax0, x0, x1); pack8(ax1, x2, x3);
        f32x4 z0 = MFMA16(ax0, Bx[0][0], bias4[0]); z0 = MFMA16(ax1, Bx[0][1], z0);
        f32x4 z1 = MFMA16(ax0, Bx[1][0], bias4[1]); z1 = MFMA16(ax1, Bx[1][1], z1);
        f32x4 z2 = MFMA16(ax0, Bx[2][0], bias4[2]); z2 = MFMA16(ax1, Bx[2][1], z2);
        f32x4 z3 = MFMA16(ax0, Bx[3][0], bias4[3]); z3 = MFMA16(ax1, Bx[3][1], z3);
        // scatter to wave-private sXZ: row = 4g+r (D-layout), unit j
#pragma unroll
        for (int r = 0; r < 4; ++r) {
            float4 v = {z0[r], z1[r], z2[r], z3[r]};
            *(float4*)&sXZ[w][4 * g + r][j][0] = v;
        }
        // s=0 xz read: DS in-wave program order -> consistent, no drain
        float4 xzv = *(const float4*)&sXZ[w][0][j][0];

        // prefetch next chunk's x (returns during the 16 steps below)
        if (n + 1 < NCHUNK) {
            const float* xr = xb + ((size_t)(n + 1) * CHUNK + j) * DIM + g * 8;
            x0 = *(const float4*)(xr);      x1 = *(const float4*)(xr + 4);
            x2 = *(const float4*)(xr + 32); x3 = *(const float4*)(xr + 36);
        }

        float* obn = ob + (size_t)n * CHUNK * 128;

#pragma unroll
        for (int s = 0; s < CHUNK; ++s) {
            const int pb = s & 1;
            // A-reads FIRST post-barrier (the only LDS on the critical path)
            f16x8 A0 = *(const f16x8*)&sH[pb][g * 8];
            f16x8 A1 = *(const f16x8*)&sH[pb][32 + g * 8];

            // deferred store of step t-1 (fills the A-read latency shadow)
            if (s > 0 || n > 0) {
                float* prevP = obn + (s - 1) * 128;       // s==0 -> prev chunk
                if (g == 0)      prevP[u]      = pc;       // cell out
                else if (g == 1) prevP[64 + u] = ph;       // hidden out
            }

            f32x4 h0 = MFMA16(A0, Bh[0][0], zero4); h0 = MFMA16(A1, Bh[0][1], h0);
            f32x4 h1 = MFMA16(A0, Bh[1][0], zero4); h1 = MFMA16(A1, Bh[1][1], h1);
            f32x4 h2 = MFMA16(A0, Bh[2][0], zero4); h2 = MFMA16(A1, Bh[2][1], h2);
            f32x4 h3 = MFMA16(A0, Bh[3][0], zero4); h3 = MFMA16(A1, Bh[3][1], h3);

            float zi = h0[0] + xzv.x, zf = h1[0] + xzv.y;
            float zg = h2[0] + xzv.z, zo = h3[0] + xzv.w;
            float gi = sigm2(zi), gf = sigm2(zf), go = sigm2(zo);
            float gg = fmaf(2.f, sigm2(zg), -1.f);     // zg pre-doubled
            c = fmaf(gf, c, gi * gg);
            // branch-free tanh: exp2 saturates (0/inf) -> sign implicit
            float ep = __builtin_amdgcn_exp2f(N2LOG2E * c);
            float th = fmaf(-2.f, __builtin_amdgcn_rcpf(1.f + ep), 1.f);
            float hh = go * th;

            // ---- counted-lgkm barrier sequence ----
            if (g == 2) sH[pb ^ 1][u] = (f16)hh;          // publish FIRST
            __builtin_amdgcn_sched_barrier(0);
            float4 xzn = *(const float4*)&sXZ[w][(s + 1) & 15][j][0];
            __builtin_amdgcn_sched_barrier(0);
            asm volatile("s_waitcnt lgkmcnt(1)" ::: "memory");
            __builtin_amdgcn_sched_barrier(0);
            __builtin_amdgcn_s_barrier();
            __builtin_amdgcn_sched_barrier(0);

            pc = c; ph = hh;
            xzv = xzn;
        }
    }
    // epilogue: store final step t = T-1
    {
        float* prevP = ob + (size_t)(T_STEPS - 1) * 128;
        if (g == 0)      prevP[u]      = pc;
        else if (g == 1) prevP[64 + u] = ph;
    }
}

extern "C" void kernel_launch(void* const* d_in, const int* in_sizes, int n_in,
                              void* d_out, int out_size, void* d_ws, size_t ws_size,
                              hipStream_t stream) {
    const float* x  = (const float*)d_in[0];
    const float* Wx = (const float*)d_in[1];
    const float* Wh = (const float*)d_in[2];
    const float* b  = (const float*)d_in[3];
    float* out = (float*)d_out;

    hipLaunchKernelGGL(lstm_final_kernel, dim3(256), dim3(256), 0, stream,
                       x, Wx, Wh, b, out);
}